// Round 2
// baseline (130.421 us; speedup 1.0000x reference)
//
#include <hip/hip_runtime.h>
#include <stdint.h>

#define HASH_MASK 524287u        // HASHMAP_SIZE - 1
#define PRIME1 2654435761u
#define PRIME2 805459861u
#define RES 128.0f

typedef float f4 __attribute__((ext_vector_type(4)));

__global__ __launch_bounds__(256) void hashgrid_fwd(
    const float* __restrict__ x,    // N*3 fp32
    const float* __restrict__ emb,  // H*2 fp32
    float* __restrict__ out,        // N*2 fp32
    int nthreads)                   // N/4
{
    int t = blockIdx.x * blockDim.x + threadIdx.x;
    if (t >= nthreads) return;

    // 4 points = 12 floats = 3 coalesced float4 loads (nontemporal: streaming)
    const f4* xv = reinterpret_cast<const f4*>(x) + (size_t)t * 3;
    f4 a = __builtin_nontemporal_load(xv);
    f4 b = __builtin_nontemporal_load(xv + 1);
    f4 c = __builtin_nontemporal_load(xv + 2);

    const float px[12] = {a.x, a.y, a.z, a.w,
                          b.x, b.y, b.z, b.w,
                          c.x, c.y, c.z, c.w};

    // ---- Phase 1: all 32 hash indices (and save fractional parts) ----
    uint32_t hid[32];
    float txf[4], tyf[4], tzf[4];
    #pragma unroll
    for (int p = 0; p < 4; ++p) {
        float fx = px[p * 3 + 0] * RES;
        float fy = px[p * 3 + 1] * RES;
        float fz = px[p * 3 + 2] * RES;
        float flx = floorf(fx), fly = floorf(fy), flz = floorf(fz);
        int ix = (int)flx, iy = (int)fly, iz = (int)flz;
        txf[p] = fx - flx;
        tyf[p] = fy - fly;
        tzf[p] = fz - flz;

        uint32_t h0a = (uint32_t)ix;          // * 1
        uint32_t h0b = h0a + 1u;
        uint32_t h1a = (uint32_t)iy * PRIME1;
        uint32_t h1b = h1a + PRIME1;
        uint32_t h2a = (uint32_t)iz * PRIME2;
        uint32_t h2b = h2a + PRIME2;

        #pragma unroll
        for (int n = 0; n < 8; ++n) {
            // bit d of n clear -> lower index in dim d (matches BIN_MASK)
            uint32_t h = ((n & 1) ? h0b : h0a)
                       ^ ((n & 2) ? h1b : h1a)
                       ^ ((n & 4) ? h2b : h2a);
            hid[p * 8 + n] = h & HASH_MASK;
        }
    }

    // ---- Phase 2: issue ALL 32 gathers (maximize loads in flight) ----
    const float2* __restrict__ embv = reinterpret_cast<const float2*>(emb);
    float2 e[32];
    #pragma unroll
    for (int i = 0; i < 32; ++i) e[i] = embv[hid[i]];

    // ---- Phase 3: weights (VALU work overlaps gather latency) ----
    float wgt[32];
    #pragma unroll
    for (int p = 0; p < 4; ++p) {
        float wxa = 1.0f - txf[p], wxb = txf[p];
        float wya = 1.0f - tyf[p], wyb = tyf[p];
        float wza = 1.0f - tzf[p], wzb = tzf[p];
        #pragma unroll
        for (int n = 0; n < 8; ++n) {
            wgt[p * 8 + n] = (((n & 1) ? wxb : wxa) * ((n & 2) ? wyb : wya))
                             * ((n & 4) ? wzb : wza);
        }
    }

    // ---- Phase 4: accumulate (compiler stages vmcnt waits in load order) ----
    float s[8];
    #pragma unroll
    for (int p = 0; p < 4; ++p) {
        float s0 = 0.0f, s1 = 0.0f;
        #pragma unroll
        for (int n = 0; n < 8; ++n) {
            s0 = fmaf(e[p * 8 + n].x, wgt[p * 8 + n], s0);
            s1 = fmaf(e[p * 8 + n].y, wgt[p * 8 + n], s1);
        }
        s[p * 2 + 0] = s0;
        s[p * 2 + 1] = s1;
    }

    // 4 points * float2 = 2 coalesced float4 stores (nontemporal)
    f4* ov = reinterpret_cast<f4*>(out) + (size_t)t * 2;
    f4 o0 = {s[0], s[1], s[2], s[3]};
    f4 o1 = {s[4], s[5], s[6], s[7]};
    __builtin_nontemporal_store(o0, ov);
    __builtin_nontemporal_store(o1, ov + 1);
}

extern "C" void kernel_launch(void* const* d_in, const int* in_sizes, int n_in,
                              void* d_out, int out_size, void* d_ws, size_t ws_size,
                              hipStream_t stream) {
    const float* x   = (const float*)d_in[0];   // N*3
    const float* emb = (const float*)d_in[1];   // H*2
    float* out = (float*)d_out;                 // N*2

    int npts = in_sizes[0] / 3;                 // 4,000,000
    int nthreads = npts / 4;                    // 1,000,000
    int block = 256;
    int grid = (nthreads + block - 1) / block;  // 3907

    hashgrid_fwd<<<grid, block, 0, stream>>>(x, emb, out, nthreads);
}

// Round 3
// 121.795 us; speedup vs baseline: 1.0708x; 1.0708x over previous
//
#include <hip/hip_runtime.h>
#include <stdint.h>

#define HASH_MASK 524287u        // HASHMAP_SIZE - 1
#define PRIME1 2654435761u
#define PRIME2 805459861u
#define RES 128.0f

typedef float f4 __attribute__((ext_vector_type(4)));

__global__ __launch_bounds__(256) void hashgrid_fwd(
    const float* __restrict__ x,    // N*3 fp32
    const float* __restrict__ emb,  // H*2 fp32
    float* __restrict__ out,        // N*2 fp32
    int nthreads)                   // N/4
{
    int t = blockIdx.x * blockDim.x + threadIdx.x;
    if (t >= nthreads) return;

    // 4 points = 12 floats = 3 coalesced float4 loads (nontemporal: streaming)
    const f4* xv = reinterpret_cast<const f4*>(x) + (size_t)t * 3;
    f4 a = __builtin_nontemporal_load(xv);
    f4 b = __builtin_nontemporal_load(xv + 1);
    f4 c = __builtin_nontemporal_load(xv + 2);

    const float px[12] = {a.x, a.y, a.z, a.w,
                          b.x, b.y, b.z, b.w,
                          c.x, c.y, c.z, c.w};

    // ---- Phase 1: all 32 hash indices (and save fractional parts) ----
    uint32_t hid[32];
    float txf[4], tyf[4], tzf[4];
    #pragma unroll
    for (int p = 0; p < 4; ++p) {
        float fx = px[p * 3 + 0] * RES;
        float fy = px[p * 3 + 1] * RES;
        float fz = px[p * 3 + 2] * RES;
        float flx = floorf(fx), fly = floorf(fy), flz = floorf(fz);
        int ix = (int)flx, iy = (int)fly, iz = (int)flz;
        txf[p] = fx - flx;
        tyf[p] = fy - fly;
        tzf[p] = fz - flz;

        uint32_t h0a = (uint32_t)ix;          // * 1
        uint32_t h0b = h0a + 1u;
        uint32_t h1a = (uint32_t)iy * PRIME1;
        uint32_t h1b = h1a + PRIME1;
        uint32_t h2a = (uint32_t)iz * PRIME2;
        uint32_t h2b = h2a + PRIME2;

        #pragma unroll
        for (int n = 0; n < 8; ++n) {
            // bit d of n clear -> lower index in dim d (matches BIN_MASK)
            uint32_t h = ((n & 1) ? h0b : h0a)
                       ^ ((n & 2) ? h1b : h1a)
                       ^ ((n & 4) ? h2b : h2a);
            hid[p * 8 + n] = h & HASH_MASK;
        }
    }

    // ---- Phase 2: issue ALL 32 gathers, then HARD FENCE so the scheduler
    // cannot sink any load past it (forces 32 loads in flight per wave) ----
    const float2* __restrict__ embv = reinterpret_cast<const float2*>(emb);
    float2 e[32];
    #pragma unroll
    for (int i = 0; i < 32; ++i) e[i] = embv[hid[i]];
    __builtin_amdgcn_sched_barrier(0);   // nothing crosses: all 32 loads issued

    // ---- Phase 3: weights (VALU work overlaps gather latency) ----
    float wgt[32];
    #pragma unroll
    for (int p = 0; p < 4; ++p) {
        float wxa = 1.0f - txf[p], wxb = txf[p];
        float wya = 1.0f - tyf[p], wyb = tyf[p];
        float wza = 1.0f - tzf[p], wzb = tzf[p];
        #pragma unroll
        for (int n = 0; n < 8; ++n) {
            wgt[p * 8 + n] = (((n & 1) ? wxb : wxa) * ((n & 2) ? wyb : wya))
                             * ((n & 4) ? wzb : wza);
        }
    }

    // ---- Phase 4: accumulate (staged vmcnt waits in load-return order) ----
    float s[8];
    #pragma unroll
    for (int p = 0; p < 4; ++p) {
        float s0 = 0.0f, s1 = 0.0f;
        #pragma unroll
        for (int n = 0; n < 8; ++n) {
            s0 = fmaf(e[p * 8 + n].x, wgt[p * 8 + n], s0);
            s1 = fmaf(e[p * 8 + n].y, wgt[p * 8 + n], s1);
        }
        s[p * 2 + 0] = s0;
        s[p * 2 + 1] = s1;
    }

    // 4 points * float2 = 2 coalesced float4 stores (nontemporal)
    f4* ov = reinterpret_cast<f4*>(out) + (size_t)t * 2;
    f4 o0 = {s[0], s[1], s[2], s[3]};
    f4 o1 = {s[4], s[5], s[6], s[7]};
    __builtin_nontemporal_store(o0, ov);
    __builtin_nontemporal_store(o1, ov + 1);
}

extern "C" void kernel_launch(void* const* d_in, const int* in_sizes, int n_in,
                              void* d_out, int out_size, void* d_ws, size_t ws_size,
                              hipStream_t stream) {
    const float* x   = (const float*)d_in[0];   // N*3
    const float* emb = (const float*)d_in[1];   // H*2
    float* out = (float*)d_out;                 // N*2

    int npts = in_sizes[0] / 3;                 // 4,000,000
    int nthreads = npts / 4;                    // 1,000,000
    int block = 256;
    int grid = (nthreads + block - 1) / block;  // 3907

    hashgrid_fwd<<<grid, block, 0, stream>>>(x, emb, out, nthreads);
}

// Round 4
// 97.426 us; speedup vs baseline: 1.3387x; 1.2501x over previous
//
#include <hip/hip_runtime.h>
#include <stdint.h>

#define HASH_MASK 524287u        // HASHMAP_SIZE - 1
#define PRIME1 2654435761u
#define PRIME2 805459861u
#define RES 128.0f

typedef float f4 __attribute__((ext_vector_type(4)));
typedef float f2 __attribute__((ext_vector_type(2)));

__global__ __launch_bounds__(256) void hashgrid_fwd(
    const float* __restrict__ x,    // N*3 fp32
    const float* __restrict__ emb,  // H*2 fp32
    float* __restrict__ out,        // N*2 fp32
    int nthreads)                   // N/4
{
    int t = blockIdx.x * blockDim.x + threadIdx.x;
    if (t >= nthreads) return;

    // 4 points = 12 floats = 3 coalesced float4 loads (nontemporal stream)
    const f4* xv = reinterpret_cast<const f4*>(x) + (size_t)t * 3;
    f4 a = __builtin_nontemporal_load(xv);
    f4 b = __builtin_nontemporal_load(xv + 1);
    f4 c = __builtin_nontemporal_load(xv + 2);

    const float px[12] = {a.x, a.y, a.z, a.w,
                          b.x, b.y, b.z, b.w,
                          c.x, c.y, c.z, c.w};

    // ---- Phase 1: all 32 byte offsets + fractional parts ----
    uint32_t off[32];
    float txf[4], tyf[4], tzf[4];
    #pragma unroll
    for (int p = 0; p < 4; ++p) {
        float fx = px[p * 3 + 0] * RES;
        float fy = px[p * 3 + 1] * RES;
        float fz = px[p * 3 + 2] * RES;
        float flx = floorf(fx), fly = floorf(fy), flz = floorf(fz);
        int ix = (int)flx, iy = (int)fly, iz = (int)flz;
        txf[p] = fx - flx;
        tyf[p] = fy - fly;
        tzf[p] = fz - flz;

        uint32_t h0a = (uint32_t)ix;          // * 1
        uint32_t h0b = h0a + 1u;
        uint32_t h1a = (uint32_t)iy * PRIME1;
        uint32_t h1b = h1a + PRIME1;
        uint32_t h2a = (uint32_t)iz * PRIME2;
        uint32_t h2b = h2a + PRIME2;

        #pragma unroll
        for (int n = 0; n < 8; ++n) {
            // bit d of n clear -> lower index in dim d (matches BIN_MASK)
            uint32_t h = ((n & 1) ? h0b : h0a)
                       ^ ((n & 2) ? h1b : h1a)
                       ^ ((n & 4) ? h2b : h2a);
            off[p * 8 + n] = (h & HASH_MASK) << 3;   // float2 = 8 bytes
        }
    }

    // ---- Phase 2: 32 gathers via inline asm (saddr form: 32b voffset +
    // SGPR base). asm volatile keeps issue order; 64 "=v" result VGPRs are
    // forced live -> 32 loads genuinely in flight per wave. ----
    f2 e[32];
    #pragma unroll
    for (int i = 0; i < 32; ++i) {
        asm volatile("global_load_dwordx2 %0, %1, %2"
                     : "=v"(e[i])
                     : "v"(off[i]), "s"(emb));
    }

    // ---- Phase 3: weights (VALU under the vmcnt shadow) ----
    float wgt[32];
    #pragma unroll
    for (int p = 0; p < 4; ++p) {
        float wxa = 1.0f - txf[p], wxb = txf[p];
        float wya = 1.0f - tyf[p], wyb = tyf[p];
        float wza = 1.0f - tzf[p], wzb = tzf[p];
        #pragma unroll
        for (int n = 0; n < 8; ++n) {
            wgt[p * 8 + n] = (((n & 1) ? wxb : wxa) * ((n & 2) ? wyb : wya))
                             * ((n & 4) ? wzb : wza);
        }
    }

    // ---- Phase 4: staged consumption. vmcnt returns are in issue order:
    // vmcnt(24) -> point 0's 8 loads done, etc. sched_barrier(0) after each
    // wait pins consumers below it (rule #18: asm waitcnt alone is hoistable).
    float s[8];

    asm volatile("s_waitcnt vmcnt(24)" ::: "memory");
    __builtin_amdgcn_sched_barrier(0);
    {
        float s0 = 0.0f, s1 = 0.0f;
        #pragma unroll
        for (int n = 0; n < 8; ++n) {
            s0 = fmaf(e[n].x, wgt[n], s0);
            s1 = fmaf(e[n].y, wgt[n], s1);
        }
        s[0] = s0; s[1] = s1;
    }

    asm volatile("s_waitcnt vmcnt(16)" ::: "memory");
    __builtin_amdgcn_sched_barrier(0);
    {
        float s0 = 0.0f, s1 = 0.0f;
        #pragma unroll
        for (int n = 0; n < 8; ++n) {
            s0 = fmaf(e[8 + n].x, wgt[8 + n], s0);
            s1 = fmaf(e[8 + n].y, wgt[8 + n], s1);
        }
        s[2] = s0; s[3] = s1;
    }

    asm volatile("s_waitcnt vmcnt(8)" ::: "memory");
    __builtin_amdgcn_sched_barrier(0);
    {
        float s0 = 0.0f, s1 = 0.0f;
        #pragma unroll
        for (int n = 0; n < 8; ++n) {
            s0 = fmaf(e[16 + n].x, wgt[16 + n], s0);
            s1 = fmaf(e[16 + n].y, wgt[16 + n], s1);
        }
        s[4] = s0; s[5] = s1;
    }

    asm volatile("s_waitcnt vmcnt(0)" ::: "memory");
    __builtin_amdgcn_sched_barrier(0);
    {
        float s0 = 0.0f, s1 = 0.0f;
        #pragma unroll
        for (int n = 0; n < 8; ++n) {
            s0 = fmaf(e[24 + n].x, wgt[24 + n], s0);
            s1 = fmaf(e[24 + n].y, wgt[24 + n], s1);
        }
        s[6] = s0; s[7] = s1;
    }

    // 4 points * float2 = 2 coalesced float4 stores (nontemporal)
    f4* ov = reinterpret_cast<f4*>(out) + (size_t)t * 2;
    f4 o0 = {s[0], s[1], s[2], s[3]};
    f4 o1 = {s[4], s[5], s[6], s[7]};
    __builtin_nontemporal_store(o0, ov);
    __builtin_nontemporal_store(o1, ov + 1);
}

extern "C" void kernel_launch(void* const* d_in, const int* in_sizes, int n_in,
                              void* d_out, int out_size, void* d_ws, size_t ws_size,
                              hipStream_t stream) {
    const float* x   = (const float*)d_in[0];   // N*3
    const float* emb = (const float*)d_in[1];   // H*2
    float* out = (float*)d_out;                 // N*2

    int npts = in_sizes[0] / 3;                 // 4,000,000
    int nthreads = npts / 4;                    // 1,000,000
    int block = 256;
    int grid = (nthreads + block - 1) / block;  // 3907

    hashgrid_fwd<<<grid, block, 0, stream>>>(x, emb, out, nthreads);
}